// Round 9
// baseline (221.341 us; speedup 1.0000x reference)
//
#include <hip/hip_runtime.h>
#include <math.h>

// Problem constants (ProbAttention: B=4, L=4096, H=8, D=64, S=U=ceil(ln L)=9)
#define B_ 4
#define L_ 4096
#define H_ 8
#define D_ 64
#define S_ 9
#define U_ 9
#define VC_ 64   // vmean stage-1 chunks per batch
#define TKC_ 8   // topk stage-1 chunks per (b,h)
#define KCH_ 32  // scores: keys per block (all 8 heads at once)
#define NCHK_ (L_ / KCH_)           // 128 score chunks per (b,h) row
#define SCB_ (B_ * NCHK_)           // 512 scores blocks

#define VMBLK_ 256                  // vmean1 blocks (front of grid: streaming)
#define MBLK_ 4096                  // kernel_M blocks: B*L waves, 4 waves/block
#define FILLBLK_ 8192               // fill blocks

__device__ __forceinline__ float dot4(const float4& a, const float4& b) {
    return a.x * b.x + a.y * b.y + a.z * b.z + a.w * b.w;
}

// ---------------------------------------------------------------------------
// K1: fused vmean1 (blocks 0..255, streaming) + kernel_M (blocks 256..4351).
// kernel_M: one wave per (b,l); 8 heads of a K row are 2048B contiguous.
// r3-r5: ILP/occupancy variants all land at 43.5-44.5us -> bound by the
// random 2KB-row fetch service rate (~137MB @ 3.2TB/s). Structural floor.
// ---------------------------------------------------------------------------
__global__ void __launch_bounds__(256, 4)
kernel_M_vmean(const float* __restrict__ Q, const float* __restrict__ K,
               const int* __restrict__ idx, float* __restrict__ M,
               const float* __restrict__ V, float* __restrict__ vpart) {
    if (blockIdx.x < VMBLK_) {
        int blk = blockIdx.x;
        int c = blk & (VC_ - 1), b = blk >> 6;
        int col = threadIdx.x & 127;
        int lp  = threadIdx.x >> 7;
        const int CHUNK = L_ / VC_;
        const float4* base = (const float4*)(V + (size_t)b * L_ * H_ * D_);
        float4 acc = make_float4(0.f, 0.f, 0.f, 0.f);
        for (int l = c * CHUNK + lp; l < (c + 1) * CHUNK; l += 2) {
            float4 v = base[(size_t)l * 128 + col];
            acc.x += v.x; acc.y += v.y; acc.z += v.z; acc.w += v.w;
        }
        __shared__ float4 red[256];
        red[threadIdx.x] = acc;
        __syncthreads();
        if (lp == 0) {
            float4 o = red[threadIdx.x + 128];
            acc.x += o.x; acc.y += o.y; acc.z += o.z; acc.w += o.w;
            ((float4*)vpart)[(size_t)blk * 128 + col] = acc;
        }
        return;
    }
    int t = threadIdx.x;
    int wid = t >> 6, lane = t & 63;
    int w = ((blockIdx.x - VMBLK_) << 2) + wid; // 0..16383 = b*L + l
    int b = __builtin_amdgcn_readfirstlane(w >> 12);
    int l = __builtin_amdgcn_readfirstlane(w & (L_ - 1));

    int ki[S_];
#pragma unroll
    for (int s = 0; s < S_; ++s) ki[s] = idx[l * S_ + s];

    const float4* qb = (const float4*)(Q + (size_t)(b * L_ + l) * (H_ * D_));
    float4 q0 = qb[2 * lane];
    float4 q1 = qb[2 * lane + 1];

    const float* Kb = K + (size_t)b * L_ * (H_ * D_);

    float4 ka[S_], kc[S_];
#pragma unroll
    for (int s = 0; s < S_; ++s) {
        const float4* kp = (const float4*)(Kb + (size_t)ki[s] * (H_ * D_));
        ka[s] = kp[2 * lane];
        kc[s] = kp[2 * lane + 1];
    }

    float mx = -INFINITY, sm = 0.0f;
#pragma unroll
    for (int s = 0; s < S_; ++s) {
        float d = dot4(q0, ka[s]) + dot4(q1, kc[s]);
        d += __shfl_xor(d, 1);
        d += __shfl_xor(d, 2);
        d += __shfl_xor(d, 4);
        mx = fmaxf(mx, d);
        sm += d;
    }
    if ((lane & 7) == 0) {
        int h = lane >> 3;
        M[((size_t)(b * H_ + h) << 12) + l] = mx - sm * (1.0f / (float)L_);
    }
}

#define CSWAP(a, b)                                                          \
    if (v[b] > v[a] || (v[b] == v[a] && id[b] < id[a])) {                    \
        float tv = v[a]; v[a] = v[b]; v[b] = tv;                             \
        int ti = id[a]; id[a] = id[b]; id[b] = ti;                           \
    }

// ---------------------------------------------------------------------------
// K2: FUSED topk (blocks 0..31, one block per bh) + vmean2 (blocks 32..63).
// topk: 4 waves x 2 passes each run the 512-element top-9 extraction
// (value desc, index asc — matches jax.lax.top_k); 72 candidates go to LDS;
// wave 0 then runs the final top-9 over the candidates -> Mtop.
// Replaces the old topk1 kernel + half of kernel_small (one launch less,
// no cand_v/cand_i global round-trip).
// ---------------------------------------------------------------------------
__global__ void kernel_topk(const float* __restrict__ M, int* __restrict__ Mtop,
                            const float* __restrict__ vpart, float* __restrict__ vmean) {
    int t = threadIdx.x;
    if (blockIdx.x >= 32) {
        // ---- vmean2: 4-way parallel over stage-1 chunks ----
        int bh = blockIdx.x - 32;
        int h = bh & (H_ - 1), b = bh >> 3;
        int d = t & 63, q = t >> 6;
        float s = 0.0f;
        for (int c = q; c < VC_; c += 4)
            s += vpart[(size_t)(b * VC_ + c) * (H_ * D_) + h * D_ + d];
        __shared__ float vr[4][64];
        vr[q][d] = s;
        __syncthreads();
        if (t < 64)
            vmean[bh * D_ + t] = (vr[0][t] + vr[1][t] + vr[2][t] + vr[3][t])
                                 * (1.0f / (float)L_);
        return;
    }
    int bh = blockIdx.x;
    int w = t >> 6, lane = t & 63;
    const float* Ms = M + ((size_t)bh << 12);

    __shared__ float cvl[TKC_ * U_];   // 72 candidates
    __shared__ int   cil[TKC_ * U_];

#pragma unroll
    for (int pass = 0; pass < 2; ++pass) {
        int chunk = w * 2 + pass;
        float v[8]; int id[8];
#pragma unroll
        for (int c = 0; c < 8; ++c) {
            int gi = chunk * 512 + lane + 64 * c;
            v[c] = Ms[gi]; id[c] = gi;
        }
        CSWAP(0,1) CSWAP(2,3) CSWAP(4,5) CSWAP(6,7)
        CSWAP(0,2) CSWAP(1,3) CSWAP(4,6) CSWAP(5,7)
        CSWAP(1,2) CSWAP(5,6)
        CSWAP(0,4) CSWAP(1,5) CSWAP(2,6) CSWAP(3,7)
        CSWAP(2,4) CSWAP(3,5)
        CSWAP(1,2) CSWAP(3,4) CSWAP(5,6)
#pragma unroll
        for (int r = 0; r < U_; ++r) {
            float bv = v[0]; int bi = id[0];
#pragma unroll
            for (int off = 1; off < 64; off <<= 1) {
                float ov = __shfl_xor(bv, off);
                int   oi = __shfl_xor(bi, off);
                if (ov > bv || (ov == bv && oi < bi)) { bv = ov; bi = oi; }
            }
            if (lane == 0) { cvl[chunk * U_ + r] = bv; cil[chunk * U_ + r] = bi; }
            if (id[0] == bi) {
#pragma unroll
                for (int c = 0; c < 7; ++c) { v[c] = v[c+1]; id[c] = id[c+1]; }
                v[7] = -INFINITY; id[7] = 0x7fffffff;
            }
        }
    }
    __syncthreads();

    if (w == 0) {
        float v[2]; int id[2];
        v[0] = cvl[lane]; id[0] = cil[lane];
        if (lane < TKC_ * U_ - 64) { v[1] = cvl[64 + lane]; id[1] = cil[64 + lane]; }
        else { v[1] = -INFINITY; id[1] = 0x7fffffff; }
        CSWAP(0,1)
#pragma unroll
        for (int r = 0; r < U_; ++r) {
            float bv = v[0]; int bi = id[0];
#pragma unroll
            for (int off = 1; off < 64; off <<= 1) {
                float ov = __shfl_xor(bv, off);
                int   oi = __shfl_xor(bi, off);
                if (ov > bv || (ov == bv && oi < bi)) { bv = ov; bi = oi; }
            }
            if (lane == 0) Mtop[bh * U_ + r] = bi;
            if (id[0] == bi) { v[0] = v[1]; id[0] = id[1];
                               v[1] = -INFINITY; id[1] = 0x7fffffff; }
        }
    }
}

// ---------------------------------------------------------------------------
// K3: fused fill (blocks 0..8191) + scores_raw (blocks 8192..8703).
// scores_raw: one block per (b, 32-key chunk), ALL 8 HEADS per wave (K rows
// read as contiguous 2KB). Emits per-(row,chunk) softmax stats (max, sumexp)
// so softmax finalization fuses into the ctx kernel.
// ---------------------------------------------------------------------------
__global__ void __launch_bounds__(256, 4)
kernel_fill_scores(float* __restrict__ out, const float* __restrict__ vmean,
                   const float* __restrict__ Q, const float* __restrict__ K,
                   const int* __restrict__ Mtop, float* __restrict__ raw,
                   float* __restrict__ stats) {
    if (blockIdx.x < FILLBLK_) {
        int i = blockIdx.x * 256 + threadIdx.x;
        int d4 = i & 15;
        int h  = (i >> 4) & (H_ - 1);
        int b  = i >> (4 + 3 + 12);
        ((float4*)out)[i] = ((const float4*)vmean)[(b * H_ + h) * 16 + d4];
        return;
    }
    int n = blockIdx.x - FILLBLK_;       // 0..511
    int b = n >> 7;                      // NCHK_=128 chunks per batch
    int chunk = n & 127;
    int k0 = chunk * KCH_;

    int t = threadIdx.x;
    int w = t >> 6, lane = t & 63;
    int h = lane >> 3, dq = lane & 7;
    int bh = b * H_ + h;

    float4 q0[U_], q1[U_];
#pragma unroll
    for (int u = 0; u < U_; ++u) {
        int mi = Mtop[bh * U_ + u];
        const float4* qp = (const float4*)(Q + (size_t)((b * L_ + mi) * H_ + h) * D_);
        q0[u] = qp[2 * dq];
        q1[u] = qp[2 * dq + 1];
    }

    __shared__ float sc[H_][U_][KCH_ + 1];

    const float* Kb = K + (size_t)b * L_ * (H_ * D_);
    const float4* kp = (const float4*)(Kb + (size_t)(k0 + w * 8) * (H_ * D_));
    float4 kv0 = kp[2 * lane], kv1 = kp[2 * lane + 1];
#pragma unroll
    for (int i = 0; i < 8; ++i) {
        int kloc = w * 8 + i;
        float4 nv0, nv1;
        if (i < 7) {
            const float4* np = (const float4*)(Kb + (size_t)(k0 + kloc + 1) * (H_ * D_));
            nv0 = np[2 * lane]; nv1 = np[2 * lane + 1];
        }
        float p[U_];
#pragma unroll
        for (int u = 0; u < U_; ++u) {
            float d = dot4(q0[u], kv0) + dot4(q1[u], kv1);
            d += __shfl_xor(d, 1);
            d += __shfl_xor(d, 2);
            d += __shfl_xor(d, 4);
            p[u] = d;
        }
        float val = p[0];
#pragma unroll
        for (int u = 1; u < 8; ++u) val = (dq == u) ? p[u] : val;
        sc[h][dq][kloc] = val;
        if (dq == 0) sc[h][8][kloc] = p[8];
        kv0 = nv0; kv1 = nv1;
    }
    __syncthreads();

#pragma unroll
    for (int r = 0; r < 9; ++r) {
        int j = r * 256 + t;
        int kloc = j & 31;
        int hu = j >> 5;
        int h2 = hu / U_, u2 = hu - h2 * U_;
        raw[((size_t)(b * H_ + h2) * U_ + u2) * L_ + k0 + kloc] =
            sc[h2][u2][kloc] * 0.125f;
    }

    if (t < H_ * U_) {
        int h2 = t / U_, u2 = t - h2 * U_;
        float mxs = -INFINITY;
#pragma unroll
        for (int k = 0; k < KCH_; ++k) mxs = fmaxf(mxs, sc[h2][u2][k]);
        mxs *= 0.125f;
        float se = 0.0f;
#pragma unroll
        for (int k = 0; k < KCH_; ++k) se += expf(sc[h2][u2][k] * 0.125f - mxs);
        ((float2*)stats)[(size_t)((b * H_ + h2) * U_ + u2) * NCHK_ + chunk] =
            make_float2(mxs, se);
    }
}

// ---------------------------------------------------------------------------
// K4: FUSED softmax-finalize + ctx + scatter (replaces ctxf AND ctx2).
// One block per bh (32 blocks x 1024 threads = 16 waves). Phase A:
// flash-combine the 128 chunk stats -> (gmax, 1/gsum) per row. Then for each
// of 16 x 256-key chunks: exp-normalize raw -> LDS + attn output (coalesced),
// accumulate ctx from LDS-broadcast weights. Final: 16-wave LDS reduce and
// direct scatter via Mtop. No cpart round-trip, no extra launch.
// ---------------------------------------------------------------------------
__global__ void __launch_bounds__(1024, 1)
kernel_ctxf2(float* __restrict__ attn, const float* __restrict__ stats,
             const float* __restrict__ V, const int* __restrict__ Mtop,
             float* __restrict__ out) {
    int bh = blockIdx.x;
    int h = bh & (H_ - 1), b = bh >> 3;
    int t = threadIdx.x;
    int g = t >> 6, lane = t & 63;
    int kl = lane >> 4, d4 = lane & 15;

    __shared__ float2 gstat[U_];
    __shared__ float attn_s[U_][256];
    __shared__ float4 redc[U_][16][16];

    // ---- Phase A: per-row global (max, 1/sum) from 128 chunk stats ----
    {
        int u = t >> 5, j = t & 31;
        if (u < U_) {
            const float2* srow = (const float2*)stats + (size_t)(bh * U_ + u) * NCHK_;
            float2 a = srow[j];
            float mm = a.x, ss = a.y;
#pragma unroll
            for (int c = 1; c < 4; ++c) {
                float2 b2 = srow[j + 32 * c];
                float nm = fmaxf(mm, b2.x);
                ss = ss * expf(mm - nm) + b2.y * expf(b2.x - nm);
                mm = nm;
            }
#pragma unroll
            for (int off = 1; off < 32; off <<= 1) {
                float om = __shfl_xor(mm, off, 32);
                float os = __shfl_xor(ss, off, 32);
                float nm = fmaxf(mm, om);
                ss = ss * expf(mm - nm) + os * expf(om - nm);
                mm = nm;
            }
            if (j == 0) gstat[u] = make_float2(mm, 1.0f / ss);
        }
    }
    __syncthreads();

    float4 acc[U_];
#pragma unroll
    for (int u = 0; u < U_; ++u) acc[u] = make_float4(0.f, 0.f, 0.f, 0.f);

    float* arow = attn + (size_t)bh * U_ * L_;

    for (int c = 0; c < 16; ++c) {
        int k0 = c * 256;
        // Phase B: exp-normalize 9x256 into LDS + attn out (2304 elems, 1024 thr)
#pragma unroll
        for (int r = 0; r < 3; ++r) {
            int idx = r * 1024 + t;
            if (idx < U_ * 256) {
                int u = idx >> 8, kk = idx & 255;
                float xv = arow[(size_t)u * L_ + k0 + kk];
                float av = expf(xv - gstat[u].x) * gstat[u].y;
                attn_s[u][kk] = av;
                arow[(size_t)u * L_ + k0 + kk] = av;
            }
        }
        __syncthreads();

        // Phase C: accumulate ctx over this chunk (keys from LDS broadcast)
#pragma unroll
        for (int i = 0; i < 4; ++i) {
            int kloc = (g * 4 + kl) + 64 * i;
            int k = k0 + kloc;
            float4 vv = *(const float4*)(V + (size_t)((b * L_ + k) * H_ + h) * D_ + 4 * d4);
            float av[U_];
#pragma unroll
            for (int u = 0; u < U_; ++u) av[u] = attn_s[u][kloc];
#pragma unroll
            for (int u = 0; u < U_; ++u) {
                acc[u].x += av[u] * vv.x; acc[u].y += av[u] * vv.y;
                acc[u].z += av[u] * vv.z; acc[u].w += av[u] * vv.w;
            }
        }
        __syncthreads();   // before next chunk overwrites attn_s
    }

    // reduce over kl (lanes 16,32 apart within wave)
#pragma unroll
    for (int u = 0; u < U_; ++u) {
        acc[u].x += __shfl_xor(acc[u].x, 16); acc[u].y += __shfl_xor(acc[u].y, 16);
        acc[u].z += __shfl_xor(acc[u].z, 16); acc[u].w += __shfl_xor(acc[u].w, 16);
        acc[u].x += __shfl_xor(acc[u].x, 32); acc[u].y += __shfl_xor(acc[u].y, 32);
        acc[u].z += __shfl_xor(acc[u].z, 32); acc[u].w += __shfl_xor(acc[u].w, 32);
    }
    if (kl == 0) {
#pragma unroll
        for (int u = 0; u < U_; ++u) redc[u][g][d4] = acc[u];
    }
    __syncthreads();

    // final: sum 16 wave-partials, scatter to out via Mtop
    if (t < U_ * 16) {
        int u = t >> 4, dd = t & 15;
        float4 s = make_float4(0.f, 0.f, 0.f, 0.f);
#pragma unroll
        for (int gg = 0; gg < 16; ++gg) {
            float4 p = redc[u][gg][dd];
            s.x += p.x; s.y += p.y; s.z += p.z; s.w += p.w;
        }
        int l = Mtop[bh * U_ + u];
        ((float4*)(out + (size_t)((b * L_ + l) * H_ + h) * D_))[dd] = s;
    }
}

extern "C" void kernel_launch(void* const* d_in, const int* in_sizes, int n_in,
                              void* d_out, int out_size, void* d_ws, size_t ws_size,
                              hipStream_t stream) {
    const float* Q   = (const float*)d_in[0];
    const float* K   = (const float*)d_in[1];
    const float* V   = (const float*)d_in[2];
    const int*   idx = (const int*)d_in[3];

    float* ctx_out  = (float*)d_out;                               // B*L*H*D
    float* attn_out = (float*)d_out + (size_t)B_ * L_ * H_ * D_;   // B*H*U*L

    // workspace (floats): M | vpart | vmean | Mtop | stats
    float* M      = (float*)d_ws;                                   // 131072
    float* vpart  = M + (size_t)B_ * H_ * L_;                       // 131072
    float* vmean  = vpart + (size_t)B_ * VC_ * H_ * D_;             // 2048
    int*   Mtop   = (int*)(vmean + B_ * H_ * D_);                   // 288
    float* stats  = (float*)(Mtop + 32 * U_);                       // 73728

    kernel_M_vmean<<<VMBLK_ + MBLK_, 256, 0, stream>>>(Q, K, idx, M, V, vpart);
    kernel_topk<<<64, 256, 0, stream>>>(M, Mtop, vpart, vmean);
    kernel_fill_scores<<<FILLBLK_ + SCB_, 256, 0, stream>>>(ctx_out, vmean, Q, K, Mtop,
                                                            attn_out, stats);
    kernel_ctxf2<<<32, 1024, 0, stream>>>(attn_out, stats, V, Mtop, ctx_out);
}

// Round 10
// 192.449 us; speedup vs baseline: 1.1501x; 1.1501x over previous
//
#include <hip/hip_runtime.h>
#include <math.h>

// Problem constants (ProbAttention: B=4, L=4096, H=8, D=64, S=U=ceil(ln L)=9)
#define B_ 4
#define L_ 4096
#define H_ 8
#define D_ 64
#define S_ 9
#define U_ 9
#define VC_ 64   // vmean stage-1 chunks per batch
#define CC_ 16   // ctx    chunks per (b,h)  (chunk = 256 keys)
#define TKC_ 8   // topk stage-1 chunks per (b,h)
#define KCH_ 32  // scores: keys per block (all 8 heads at once)
#define NCHK_ (L_ / KCH_)           // 128 score chunks per (b,h) row
#define SCB_ (B_ * NCHK_)           // 512 scores blocks

#define VMBLK_ 256                  // vmean1 blocks (front of grid: streaming)
#define MBLK_ 4096                  // kernel_M blocks: B*L waves, 4 waves/block
#define FILLBLK_ 8192               // fill blocks

__device__ __forceinline__ float dot4(const float4& a, const float4& b) {
    return a.x * b.x + a.y * b.y + a.z * b.z + a.w * b.w;
}

// ---------------------------------------------------------------------------
// K1: fused vmean1 (blocks 0..255, streaming) + kernel_M (blocks 256..4351).
// kernel_M: one wave per (b,l); 8 heads of a K row are 2048B contiguous.
// r3-r5: ILP/occupancy variants (sched_barrier, asm use-fence, launch_bounds)
// all land at 43.5-44.5us regardless of VGPR(32/48) and occupancy(45-65%)
// -> bound by the random 2KB-row fetch service rate (~137MB HBM miss @
// 3.2TB/s + ~300MB L3-served gather). Structural floor for this access.
// r9: back-half parallelism >> launch-count: keep wide grids, 6 launches.
// ---------------------------------------------------------------------------
__global__ void __launch_bounds__(256, 4)
kernel_M_vmean(const float* __restrict__ Q, const float* __restrict__ K,
               const int* __restrict__ idx, float* __restrict__ M,
               const float* __restrict__ V, float* __restrict__ vpart) {
    if (blockIdx.x < VMBLK_) {
        int blk = blockIdx.x;
        int c = blk & (VC_ - 1), b = blk >> 6;
        int col = threadIdx.x & 127;
        int lp  = threadIdx.x >> 7;
        const int CHUNK = L_ / VC_;
        const float4* base = (const float4*)(V + (size_t)b * L_ * H_ * D_);
        float4 acc = make_float4(0.f, 0.f, 0.f, 0.f);
        for (int l = c * CHUNK + lp; l < (c + 1) * CHUNK; l += 2) {
            float4 v = base[(size_t)l * 128 + col];
            acc.x += v.x; acc.y += v.y; acc.z += v.z; acc.w += v.w;
        }
        __shared__ float4 red[256];
        red[threadIdx.x] = acc;
        __syncthreads();
        if (lp == 0) {
            float4 o = red[threadIdx.x + 128];
            acc.x += o.x; acc.y += o.y; acc.z += o.z; acc.w += o.w;
            ((float4*)vpart)[(size_t)blk * 128 + col] = acc;
        }
        return;
    }
    int t = threadIdx.x;
    int wid = t >> 6, lane = t & 63;
    int w = ((blockIdx.x - VMBLK_) << 2) + wid; // 0..16383 = b*L + l
    int b = __builtin_amdgcn_readfirstlane(w >> 12);
    int l = __builtin_amdgcn_readfirstlane(w & (L_ - 1));

    int ki[S_];
#pragma unroll
    for (int s = 0; s < S_; ++s) ki[s] = idx[l * S_ + s];

    const float4* qb = (const float4*)(Q + (size_t)(b * L_ + l) * (H_ * D_));
    float4 q0 = qb[2 * lane];
    float4 q1 = qb[2 * lane + 1];

    const float* Kb = K + (size_t)b * L_ * (H_ * D_);

    float4 ka[S_], kc[S_];
#pragma unroll
    for (int s = 0; s < S_; ++s) {
        const float4* kp = (const float4*)(Kb + (size_t)ki[s] * (H_ * D_));
        ka[s] = kp[2 * lane];
        kc[s] = kp[2 * lane + 1];
    }

    float mx = -INFINITY, sm = 0.0f;
#pragma unroll
    for (int s = 0; s < S_; ++s) {
        float d = dot4(q0, ka[s]) + dot4(q1, kc[s]);
        d += __shfl_xor(d, 1);
        d += __shfl_xor(d, 2);
        d += __shfl_xor(d, 4);
        mx = fmaxf(mx, d);
        sm += d;
    }
    if ((lane & 7) == 0) {
        int h = lane >> 3;
        M[((size_t)(b * H_ + h) << 12) + l] = mx - sm * (1.0f / (float)L_);
    }
}

// ---------------------------------------------------------------------------
// Top-k stage 1 (value desc, index asc) — matches jax.lax.top_k.
// 256 blocks: wide grid (r9 lesson — do NOT narrow this for launch savings).
// ---------------------------------------------------------------------------
#define CSWAP(a, b)                                                          \
    if (v[b] > v[a] || (v[b] == v[a] && id[b] < id[a])) {                    \
        float tv = v[a]; v[a] = v[b]; v[b] = tv;                             \
        int ti = id[a]; id[a] = id[b]; id[b] = ti;                           \
    }

__global__ void kernel_topk1(const float* __restrict__ M,
                             float* __restrict__ cand_v, int* __restrict__ cand_i) {
    int bh = blockIdx.x >> 3;
    int chunk = blockIdx.x & (TKC_ - 1);
    int lane = threadIdx.x;
    const float* Ms = M + ((size_t)bh << 12);

    float v[8]; int id[8];
#pragma unroll
    for (int c = 0; c < 8; ++c) {
        int gi = chunk * 512 + lane + 64 * c;
        v[c] = Ms[gi]; id[c] = gi;
    }
    CSWAP(0,1) CSWAP(2,3) CSWAP(4,5) CSWAP(6,7)
    CSWAP(0,2) CSWAP(1,3) CSWAP(4,6) CSWAP(5,7)
    CSWAP(1,2) CSWAP(5,6)
    CSWAP(0,4) CSWAP(1,5) CSWAP(2,6) CSWAP(3,7)
    CSWAP(2,4) CSWAP(3,5)
    CSWAP(1,2) CSWAP(3,4) CSWAP(5,6)

    float* cv = cand_v + (size_t)blockIdx.x * U_;
    int*   ci = cand_i + (size_t)blockIdx.x * U_;
#pragma unroll
    for (int r = 0; r < U_; ++r) {
        float bv = v[0]; int bi = id[0];
#pragma unroll
        for (int off = 1; off < 64; off <<= 1) {
            float ov = __shfl_xor(bv, off);
            int   oi = __shfl_xor(bi, off);
            if (ov > bv || (ov == bv && oi < bi)) { bv = ov; bi = oi; }
        }
        if (lane == 0) { cv[r] = bv; ci[r] = bi; }
        if (id[0] == bi) {
#pragma unroll
            for (int c = 0; c < 7; ++c) { v[c] = v[c+1]; id[c] = id[c+1]; }
            v[7] = -INFINITY; id[7] = 0x7fffffff;
        }
    }
}

// ---------------------------------------------------------------------------
// K3: fused topk2 (blocks 0..31) + vmean2 (blocks 32..63). 64 threads.
// ---------------------------------------------------------------------------
__global__ void kernel_small(const float* __restrict__ cand_v, const int* __restrict__ cand_i,
                             int* __restrict__ Mtop, const float* __restrict__ vpart,
                             float* __restrict__ vmean) {
    if (blockIdx.x >= 32) {
        int bh = blockIdx.x - 32;
        int h = bh & (H_ - 1), b = bh >> 3;
        int d = threadIdx.x;
        float s = 0.0f;
        for (int c = 0; c < VC_; ++c)
            s += vpart[(size_t)(b * VC_ + c) * (H_ * D_) + h * D_ + d];
        vmean[bh * D_ + d] = s * (1.0f / (float)L_);
        return;
    }
    int bh = blockIdx.x;
    int lane = threadIdx.x;
    const float* cv = cand_v + (size_t)bh * (TKC_ * U_);
    const int*   ci = cand_i + (size_t)bh * (TKC_ * U_);

    float v[2]; int id[2];
    v[0] = cv[lane]; id[0] = ci[lane];
    if (lane < TKC_ * U_ - 64) { v[1] = cv[64 + lane]; id[1] = ci[64 + lane]; }
    else { v[1] = -INFINITY; id[1] = 0x7fffffff; }
    CSWAP(0,1)

#pragma unroll
    for (int r = 0; r < U_; ++r) {
        float bv = v[0]; int bi = id[0];
#pragma unroll
        for (int off = 1; off < 64; off <<= 1) {
            float ov = __shfl_xor(bv, off);
            int   oi = __shfl_xor(bi, off);
            if (ov > bv || (ov == bv && oi < bi)) { bv = ov; bi = oi; }
        }
        if (lane == 0) Mtop[bh * U_ + r] = bi;
        if (id[0] == bi) { v[0] = v[1]; id[0] = id[1]; v[1] = -INFINITY; id[1] = 0x7fffffff; }
    }
}

// ---------------------------------------------------------------------------
// K4: fused fill (blocks 0..8191) + scores_raw (blocks 8192..8703).
// scores_raw: one block per (b, 32-key chunk), ALL 8 HEADS per wave (K rows
// read as contiguous 2KB). Emits per-(row,chunk) softmax stats (max, sumexp)
// so softmax finalization fuses into the ctx kernel.
// ---------------------------------------------------------------------------
__global__ void __launch_bounds__(256, 4)
kernel_fill_scores(float* __restrict__ out, const float* __restrict__ vmean,
                   const float* __restrict__ Q, const float* __restrict__ K,
                   const int* __restrict__ Mtop, float* __restrict__ raw,
                   float* __restrict__ stats) {
    if (blockIdx.x < FILLBLK_) {
        int i = blockIdx.x * 256 + threadIdx.x;
        int d4 = i & 15;
        int h  = (i >> 4) & (H_ - 1);
        int b  = i >> (4 + 3 + 12);
        ((float4*)out)[i] = ((const float4*)vmean)[(b * H_ + h) * 16 + d4];
        return;
    }
    int n = blockIdx.x - FILLBLK_;       // 0..511
    int b = n >> 7;                      // NCHK_=128 chunks per batch
    int chunk = n & 127;
    int k0 = chunk * KCH_;

    int t = threadIdx.x;
    int w = t >> 6, lane = t & 63;
    int h = lane >> 3, dq = lane & 7;
    int bh = b * H_ + h;

    float4 q0[U_], q1[U_];
#pragma unroll
    for (int u = 0; u < U_; ++u) {
        int mi = Mtop[bh * U_ + u];
        const float4* qp = (const float4*)(Q + (size_t)((b * L_ + mi) * H_ + h) * D_);
        q0[u] = qp[2 * dq];
        q1[u] = qp[2 * dq + 1];
    }

    __shared__ float sc[H_][U_][KCH_ + 1];   // +1 pad: spread h-stride over banks

    const float* Kb = K + (size_t)b * L_ * (H_ * D_);
    const float4* kp = (const float4*)(Kb + (size_t)(k0 + w * 8) * (H_ * D_));
    float4 kv0 = kp[2 * lane], kv1 = kp[2 * lane + 1];
#pragma unroll
    for (int i = 0; i < 8; ++i) {
        int kloc = w * 8 + i;
        float4 nv0, nv1;
        if (i < 7) {               // one-deep register prefetch of next row
            const float4* np = (const float4*)(Kb + (size_t)(k0 + kloc + 1) * (H_ * D_));
            nv0 = np[2 * lane]; nv1 = np[2 * lane + 1];
        }
        float p[U_];
#pragma unroll
        for (int u = 0; u < U_; ++u) {
            float d = dot4(q0[u], kv0) + dot4(q1[u], kv1);
            d += __shfl_xor(d, 1);
            d += __shfl_xor(d, 2);
            d += __shfl_xor(d, 4);
            p[u] = d;
        }
        // lane dq writes u=dq (static-index select chain, no scratch)
        float val = p[0];
#pragma unroll
        for (int u = 1; u < 8; ++u) val = (dq == u) ? p[u] : val;
        sc[h][dq][kloc] = val;
        if (dq == 0) sc[h][8][kloc] = p[8];
        kv0 = nv0; kv1 = nv1;
    }
    __syncthreads();

    // coalesced write-out: 8h*9u*32k = 2304 floats, 32-float runs per (h,u)
#pragma unroll
    for (int r = 0; r < 9; ++r) {
        int j = r * 256 + t;
        int kloc = j & 31;
        int hu = j >> 5;                 // 0..71
        int h2 = hu / U_, u2 = hu - h2 * U_;
        raw[((size_t)(b * H_ + h2) * U_ + u2) * L_ + k0 + kloc] =
            sc[h2][u2][kloc] * 0.125f;
    }

    // per-(row,chunk) softmax stats over the 32 scaled scores
    if (t < H_ * U_) {
        int h2 = t / U_, u2 = t - h2 * U_;
        float mxs = -INFINITY;
#pragma unroll
        for (int k = 0; k < KCH_; ++k) mxs = fmaxf(mxs, sc[h2][u2][k]);
        mxs *= 0.125f;
        float se = 0.0f;
#pragma unroll
        for (int k = 0; k < KCH_; ++k) se += expf(sc[h2][u2][k] * 0.125f - mxs);
        ((float2*)stats)[(size_t)((b * H_ + h2) * U_ + u2) * NCHK_ + chunk] =
            make_float2(mxs, se);
    }
}

// ---------------------------------------------------------------------------
// K6': ctx fused with SOFTMAX (replaces separate softmax + old ctxf).
// 512 blocks (wide — r9 lesson). Phase A: flash-combine 128 chunk stats per
// row -> (gmax, 1/gsum); u-loop covers row 8 (r6 fix). Phase B: attn tile =
// exp(raw-gmax)/gsum -> LDS + attn output. Phase C: ctx partials.
// ---------------------------------------------------------------------------
__global__ void kernel_ctxf(float* __restrict__ attn, const float* __restrict__ stats,
                            const float* __restrict__ V, float* __restrict__ cpart) {
    int n = blockIdx.x;
    int x = n & 7, m = n >> 3;
    int chunk = m & (CC_ - 1);
    int bh = (m >> 4) * 8 + x;       // CC_ = 16
    int h = bh & (H_ - 1), b = bh >> 3;
    int k0 = chunk * (L_ / CC_);     // 256 keys

    int t = threadIdx.x;

    // ---- Phase A: per-row global (max, 1/sum) from 128 chunk stats ----
    __shared__ float2 gstat[U_];
    int j = t & 31;
    for (int u = t >> 5; u < U_; u += 8) {   // 8 groups of 32 lanes; u=8 on 2nd pass
        const float2* srow = (const float2*)stats + (size_t)(bh * U_ + u) * NCHK_;
        float2 a = srow[j];
        float mm = a.x, ss = a.y;
#pragma unroll
        for (int c = 1; c < 4; ++c) {
            float2 b2 = srow[j + 32 * c];
            float nm = fmaxf(mm, b2.x);
            ss = ss * expf(mm - nm) + b2.y * expf(b2.x - nm);
            mm = nm;
        }
#pragma unroll
        for (int off = 1; off < 32; off <<= 1) {
            float om = __shfl_xor(mm, off, 32);
            float os = __shfl_xor(ss, off, 32);
            float nm = fmaxf(mm, om);
            ss = ss * expf(mm - nm) + os * expf(om - nm);
            mm = nm;
        }
        if (j == 0) gstat[u] = make_float2(mm, 1.0f / ss);
    }
    __syncthreads();

    // ---- Phase B: materialize attn tile (9 x 256) in LDS + write output ----
    __shared__ float attn_s[U_][256];
    float* arow = attn + (size_t)bh * U_ * L_ + k0;
#pragma unroll
    for (int u = 0; u < U_; ++u) {
        float xv = arow[(size_t)u * L_ + t];
        float av = expf(xv - gstat[u].x) * gstat[u].y;
        attn_s[u][t] = av;
        arow[(size_t)u * L_ + t] = av;
    }
    __syncthreads();

    // ---- Phase C: ctx partial accumulation (attn from LDS broadcast) ----
    int g = t >> 6, lane = t & 63;
    int kl = lane >> 4, d4 = lane & 15;

    float4 acc[U_];
#pragma unroll
    for (int u = 0; u < U_; ++u) acc[u] = make_float4(0.f, 0.f, 0.f, 0.f);

    for (int i = 0; i < 16; ++i) {
        int kloc = (g * 4 + kl) + 16 * i;
        int k = k0 + kloc;
        float4 vv = *(const float4*)(V + (size_t)((b * L_ + k) * H_ + h) * D_ + 4 * d4);
        float av[U_];
#pragma unroll
        for (int u = 0; u < U_; ++u) av[u] = attn_s[u][kloc];
#pragma unroll
        for (int u = 0; u < U_; ++u) {
            acc[u].x += av[u] * vv.x; acc[u].y += av[u] * vv.y;
            acc[u].z += av[u] * vv.z; acc[u].w += av[u] * vv.w;
        }
    }
    // reduce over kl (lanes 16,32 apart)
#pragma unroll
    for (int u = 0; u < U_; ++u) {
        acc[u].x += __shfl_xor(acc[u].x, 16); acc[u].y += __shfl_xor(acc[u].y, 16);
        acc[u].z += __shfl_xor(acc[u].z, 16); acc[u].w += __shfl_xor(acc[u].w, 16);
        acc[u].x += __shfl_xor(acc[u].x, 32); acc[u].y += __shfl_xor(acc[u].y, 32);
        acc[u].z += __shfl_xor(acc[u].z, 32); acc[u].w += __shfl_xor(acc[u].w, 32);
    }
    __shared__ float4 red[U_][4][16];
    if (kl == 0) {
#pragma unroll
        for (int u = 0; u < U_; ++u) red[u][g][d4] = acc[u];
    }
    __syncthreads();
    if (t < U_ * 16) {
        int u = t >> 4, dd = t & 15;
        float4 s0 = red[u][0][dd], s1 = red[u][1][dd];
        float4 s2 = red[u][2][dd], s3 = red[u][3][dd];
        float4 s = make_float4(s0.x + s1.x + s2.x + s3.x, s0.y + s1.y + s2.y + s3.y,
                               s0.z + s1.z + s2.z + s3.z, s0.w + s1.w + s2.w + s3.w);
        ((float4*)cpart)[((size_t)(bh * CC_ + chunk) * U_ + u) * 16 + dd] = s;
    }
}

// K7: combine + scatter. grid = B*H*U (288), 64 threads.
__global__ void kernel_ctx2(const float* __restrict__ cpart, const int* __restrict__ Mtop,
                            float* __restrict__ out) {
    int row = blockIdx.x;
    int u = row % U_, bh = row / U_;
    int h = bh & (H_ - 1), b = bh >> 3;
    int d = threadIdx.x;
    float s = 0.0f;
#pragma unroll
    for (int c = 0; c < CC_; ++c)
        s += cpart[((size_t)(bh * CC_ + c) * U_ + u) * 64 + d];
    int l = Mtop[bh * U_ + u];
    out[(size_t)((b * L_ + l) * H_ + h) * D_ + d] = s;
}

extern "C" void kernel_launch(void* const* d_in, const int* in_sizes, int n_in,
                              void* d_out, int out_size, void* d_ws, size_t ws_size,
                              hipStream_t stream) {
    const float* Q   = (const float*)d_in[0];
    const float* K   = (const float*)d_in[1];
    const float* V   = (const float*)d_in[2];
    const int*   idx = (const int*)d_in[3];

    float* ctx_out  = (float*)d_out;                               // B*L*H*D
    float* attn_out = (float*)d_out + (size_t)B_ * L_ * H_ * D_;   // B*H*U*L

    // workspace (floats): M | vpart | vmean | cpart | cand_v | cand_i | Mtop | stats
    float* M      = (float*)d_ws;                                   // 131072
    float* vpart  = M + (size_t)B_ * H_ * L_;                       // 131072
    float* vmean  = vpart + (size_t)B_ * VC_ * H_ * D_;             // 2048
    float* cpart  = vmean + B_ * H_ * D_;                           // 294912
    float* cand_v = cpart + (size_t)32 * CC_ * U_ * 64;             // 2304
    int*   cand_i = (int*)(cand_v + 32 * TKC_ * U_);                // 2304
    int*   Mtop   = cand_i + 32 * TKC_ * U_;                        // 288
    float* stats  = (float*)(Mtop + 32 * U_);                       // 73728

    kernel_M_vmean<<<VMBLK_ + MBLK_, 256, 0, stream>>>(Q, K, idx, M, V, vpart);
    kernel_topk1<<<B_ * H_ * TKC_, 64, 0, stream>>>(M, cand_v, cand_i);
    kernel_small<<<64, 64, 0, stream>>>(cand_v, cand_i, Mtop, vpart, vmean);
    kernel_fill_scores<<<FILLBLK_ + SCB_, 256, 0, stream>>>(ctx_out, vmean, Q, K, Mtop,
                                                            attn_out, stats);
    kernel_ctxf<<<32 * CC_, 256, 0, stream>>>(attn_out, stats, V, cpart);
    kernel_ctx2<<<B_ * H_ * U_, 64, 0, stream>>>(cpart, Mtop, ctx_out);
}